// Round 4
// baseline (549.789 us; speedup 1.0000x reference)
//
#include <hip/hip_runtime.h>
#include <math.h>

#define NEG_SLOPE 0.2f
#define LOG2E 1.44269504088896340736f

// ---------------------------------------------------------------------------
// AtomEncoder + edge histogram (fused). One wave per node (n forced uniform
// via readfirstlane -> feat reads become s_loads, emb gather is SGPR-base
// coalesced). First E global threads also histogram dst (counts pre-zeroed
// by memsetAsync; the self-loop "+1" is folded into the scan).
// ---------------------------------------------------------------------------
__global__ __launch_bounds__(256) void embed_kernel(
        const int* __restrict__ feat, const float* __restrict__ emb,
        const int* __restrict__ dstE, int* __restrict__ counts,
        float* __restrict__ x, int N, int E) {
    int gid = blockIdx.x * 256 + threadIdx.x;
    if (gid < E) atomicAdd(&counts[dstE[gid]], 1);

    const int offs[9] = {0, 119, 124, 136, 148, 158, 164, 170, 172};
    int sub  = threadIdx.x >> 6;
    int lane = threadIdx.x & 63;
    int n = __builtin_amdgcn_readfirstlane(blockIdx.x * 4 + sub);
    if (n >= N) return;
    float s = 0.f;
#pragma unroll
    for (int j = 0; j < 9; ++j) {
        int idx = feat[n * 9 + j] + offs[j];   // n uniform -> s_load
        s += emb[idx * 64 + lane];             // SGPR row base + lane
    }
    x[(size_t)n * 64 + lane] = s;
}

// ---------------------------------------------------------------------------
// Dual GEMM: xl = x @ Wl + bl ; xr = x @ Wr + br.  x:[N,64], W:[64,256].
// blockIdx.y in 0..3 selects (matrix, 128-col half). Tile 64x128, 256 thr,
// 8 contiguous rows x 4 cols per thread. BK=32 two-pass: LDS 24 KB/block
// (was 48) -> 6 blocks/CU instead of 3.
// ---------------------------------------------------------------------------
__global__ __launch_bounds__(256) void gemm_kernel(
        const float* __restrict__ x,
        const float* __restrict__ Wl, const float* __restrict__ Wr,
        const float* __restrict__ bl, const float* __restrict__ br,
        float* __restrict__ xl, float* __restrict__ xr, int N) {
    __shared__ __align__(16) float As[32][64];   // 8 KB  [k][m]
    __shared__ __align__(16) float Bs[32][128];  // 16 KB [k][c]
    int t  = threadIdx.x;
    int m0 = blockIdx.x * 64;
    int ct = blockIdx.y;  // 0,1 -> Wl ; 2,3 -> Wr
    const float* B    = (ct < 2) ? Wl : Wr;
    const float* bias = (ct < 2) ? bl : br;
    float*       out  = (ct < 2) ? xl : xr;
    int cb = (ct & 1) * 128;

    int m   = t & 63;
    int kq0 = t >> 6;   // 0..3
    int row = m0 + m;
    int c4  = t & 31;
    int k0  = t >> 5;   // 0..7
    int tx  = t & 31;   // col quad
    int ty  = t >> 5;   // row group: rows ty*8..+7

    float4 acc[8];
#pragma unroll
    for (int i = 0; i < 8; ++i) acc[i] = make_float4(0.f, 0.f, 0.f, 0.f);

#pragma unroll
    for (int kb = 0; kb < 2; ++kb) {
        // global loads for this K-half (before the protecting sync)
        float4 a0 = make_float4(0.f, 0.f, 0.f, 0.f), a1 = a0;
        if (row < N) {
            a0 = *(const float4*)(x + (size_t)row * 64 + (kb * 8 + kq0) * 4);
            a1 = *(const float4*)(x + (size_t)row * 64 + (kb * 8 + kq0 + 4) * 4);
        }
        float4 bv[4];
#pragma unroll
        for (int j = 0; j < 4; ++j) {
            int k = kb * 32 + k0 + j * 8;
            bv[j] = *(const float4*)(B + (size_t)k * 256 + cb + c4 * 4);
        }
        if (kb) __syncthreads();   // previous half fully consumed
        As[kq0 * 4 + 0][m] = a0.x; As[kq0 * 4 + 1][m] = a0.y;
        As[kq0 * 4 + 2][m] = a0.z; As[kq0 * 4 + 3][m] = a0.w;
        As[(kq0 + 4) * 4 + 0][m] = a1.x; As[(kq0 + 4) * 4 + 1][m] = a1.y;
        As[(kq0 + 4) * 4 + 2][m] = a1.z; As[(kq0 + 4) * 4 + 3][m] = a1.w;
#pragma unroll
        for (int j = 0; j < 4; ++j)
            *(float4*)(&Bs[k0 + j * 8][c4 * 4]) = bv[j];
        __syncthreads();

#pragma unroll 8
        for (int k = 0; k < 32; ++k) {
            float4 b   = *(const float4*)(&Bs[k][tx * 4]);
            float4 alo = *(const float4*)(&As[k][ty * 8]);
            float4 ahi = *(const float4*)(&As[k][ty * 8 + 4]);
            acc[0].x += alo.x * b.x; acc[0].y += alo.x * b.y; acc[0].z += alo.x * b.z; acc[0].w += alo.x * b.w;
            acc[1].x += alo.y * b.x; acc[1].y += alo.y * b.y; acc[1].z += alo.y * b.z; acc[1].w += alo.y * b.w;
            acc[2].x += alo.z * b.x; acc[2].y += alo.z * b.y; acc[2].z += alo.z * b.z; acc[2].w += alo.z * b.w;
            acc[3].x += alo.w * b.x; acc[3].y += alo.w * b.y; acc[3].z += alo.w * b.z; acc[3].w += alo.w * b.w;
            acc[4].x += ahi.x * b.x; acc[4].y += ahi.x * b.y; acc[4].z += ahi.x * b.z; acc[4].w += ahi.x * b.w;
            acc[5].x += ahi.y * b.x; acc[5].y += ahi.y * b.y; acc[5].z += ahi.y * b.z; acc[5].w += ahi.y * b.w;
            acc[6].x += ahi.z * b.x; acc[6].y += ahi.z * b.y; acc[6].z += ahi.z * b.z; acc[6].w += ahi.z * b.w;
            acc[7].x += ahi.w * b.x; acc[7].y += ahi.w * b.y; acc[7].z += ahi.w * b.z; acc[7].w += ahi.w * b.w;
        }
    }

    float4 bb = *(const float4*)(bias + cb + tx * 4);
#pragma unroll
    for (int i = 0; i < 8; ++i) {
        int r = m0 + ty * 8 + i;
        if (r < N) {
            float4 o = acc[i];
            o.x += bb.x; o.y += bb.y; o.z += bb.z; o.w += bb.w;
            *(float4*)(out + (size_t)r * 256 + cb + tx * 4) = o;
        }
    }
}

// ---------------------------------------------------------------------------
// CSR build. counts[] holds raw indegree; scan adds +1 per node (self loop).
// ---------------------------------------------------------------------------
__global__ void scan_block_kernel(const int* __restrict__ counts, int* __restrict__ excl,
                                  int* __restrict__ blockSums, int N) {
    __shared__ int lds[256];
    int b = blockIdx.x, t = threadIdx.x;
    int base = b * 1024 + t * 4;
    int v0 = (base + 0 < N) ? counts[base + 0] + 1 : 0;   // +1 = self loop
    int v1 = (base + 1 < N) ? counts[base + 1] + 1 : 0;
    int v2 = (base + 2 < N) ? counts[base + 2] + 1 : 0;
    int v3 = (base + 3 < N) ? counts[base + 3] + 1 : 0;
    int s = v0 + v1 + v2 + v3;
    lds[t] = s;
    __syncthreads();
    for (int off = 1; off < 256; off <<= 1) {
        int add = (t >= off) ? lds[t - off] : 0;
        __syncthreads();
        lds[t] += add;
        __syncthreads();
    }
    int run = lds[t] - s;
    if (base + 0 < N) excl[base + 0] = run; run += v0;
    if (base + 1 < N) excl[base + 1] = run; run += v1;
    if (base + 2 < N) excl[base + 2] = run; run += v2;
    if (base + 3 < N) excl[base + 3] = run;
    if (t == 255) blockSums[b] = lds[255];
}

__global__ void scan_sums_kernel(int* __restrict__ blockSums, int nb) {
    __shared__ int lds[64];
    int t = threadIdx.x;  // nb <= 64 required (N <= 65536)
    int v = (t < nb) ? blockSums[t] : 0;
    lds[t] = v;
    __syncthreads();
    for (int off = 1; off < 64; off <<= 1) {
        int add = (t >= off) ? lds[t - off] : 0;
        __syncthreads();
        lds[t] += add;
        __syncthreads();
    }
    if (t < nb) blockSums[t] = lds[t] - v;
}

__global__ void finalize_kernel(int* __restrict__ csr_off, const int* __restrict__ blockSums,
                                int* __restrict__ cursor, int* __restrict__ csr_src,
                                int N, int total) {
    int i = blockIdx.x * 256 + threadIdx.x;
    if (i < N) {
        int v = csr_off[i] + blockSums[i >> 10];
        csr_off[i] = v;
        csr_src[v] = i;    // self loop at segment head
        cursor[i]  = v + 1;
    }
    if (i == 0) csr_off[N] = total;
}

__global__ void scatter_kernel(const int* __restrict__ src, const int* __restrict__ dst,
                               int* __restrict__ cursor, int* __restrict__ csr_src, int E) {
    int e = blockIdx.x * 256 + threadIdx.x;
    if (e < E) {
        int pos = atomicAdd(&cursor[dst[e]], 1);
        csr_src[pos] = src[e];
    }
}

// ---------------------------------------------------------------------------
// GATv2 aggregation: one wave per dst node, n forced wave-uniform via
// readfirstlane -> csr_off/csr_src reads are s_loads (scalar pipe), clamps
// are SALU, xl-row gathers are SGPR-base + fixed lane offset (zero per-edge
// VALU address math). Software pipeline: group g+1's gathers + g+2's indices
// issued before computing group g. att pre-scaled by log2(e) -> exp2f.
// Clamped slots duplicate row `last` (always valid, L1-hot); accumulation
// excludes them via wave-uniform guards.
// ---------------------------------------------------------------------------
__global__ __launch_bounds__(256) void agg_kernel(
        const float* __restrict__ xl, const float* __restrict__ xr,
        const int* __restrict__ csr_off, const int* __restrict__ csr_src,
        const float* __restrict__ att,   // [4*64] this layer
        const float* __restrict__ gbias, // [64] this layer
        float* __restrict__ xout, int N, int apply_gelu) {
    int wave = threadIdx.x >> 6;
    int lane = threadIdx.x & 63;
    int n = __builtin_amdgcn_readfirstlane(blockIdx.x * 4 + wave);
    if (n >= N) return;

    float4 att4 = ((const float4*)att)[lane];
    att4.x *= LOG2E; att4.y *= LOG2E; att4.z *= LOG2E; att4.w *= LOG2E;
    float4 xr4 = *(const float4*)(xr + (size_t)n * 256 + lane * 4);
    float ax = 0.f, ay = 0.f, az = 0.f, aw = 0.f, denom = 0.f;

    int beg  = csr_off[n];        // uniform -> s_load
    int end  = csr_off[n + 1];
    int m    = end - beg;         // includes self loop, >= 1
    int last = end - 1;

    const float* __restrict__ xlp = xl + lane * 4;

    auto logit = [&](const float4& v) -> float {
        float s0 = v.x + xr4.x, s1 = v.y + xr4.y, s2 = v.z + xr4.z, s3 = v.w + xr4.w;
        float t0 = fmaxf(s0, NEG_SLOPE * s0);
        float t1 = fmaxf(s1, NEG_SLOPE * s1);
        float t2 = fmaxf(s2, NEG_SLOPE * s2);
        float t3 = fmaxf(s3, NEG_SLOPE * s3);
        return t0 * att4.x + t1 * att4.y + t2 * att4.z + t3 * att4.w;
    };

    // group 0 indices + data, group 1 indices (all clamped -> always valid)
    int i0 = csr_src[beg];
    int i1 = csr_src[min(beg + 1, last)];
    int i2 = csr_src[min(beg + 2, last)];
    int i3 = csr_src[min(beg + 3, last)];
    float4 a0 = *(const float4*)(xlp + (size_t)i0 * 256);
    float4 a1 = *(const float4*)(xlp + (size_t)i1 * 256);
    float4 a2 = *(const float4*)(xlp + (size_t)i2 * 256);
    float4 a3 = *(const float4*)(xlp + (size_t)i3 * 256);
    int j0 = csr_src[min(beg + 4, last)];
    int j1 = csr_src[min(beg + 5, last)];
    int j2 = csr_src[min(beg + 6, last)];
    int j3 = csr_src[min(beg + 7, last)];

    for (int base = 0; base < m; base += 4) {
        int rem = m - base;   // wave-uniform (SGPR)
        // prefetch next group's data + next-next indices
        float4 b0 = *(const float4*)(xlp + (size_t)j0 * 256);
        float4 b1 = *(const float4*)(xlp + (size_t)j1 * 256);
        float4 b2 = *(const float4*)(xlp + (size_t)j2 * 256);
        float4 b3 = *(const float4*)(xlp + (size_t)j3 * 256);
        int q = beg + base + 8;
        j0 = csr_src[min(q,     last)];
        j1 = csr_src[min(q + 1, last)];
        j2 = csr_src[min(q + 2, last)];
        j3 = csr_src[min(q + 3, last)];

        float p0 = logit(a0), p1 = logit(a1), p2 = logit(a2), p3 = logit(a3);
        p0 += __shfl_xor(p0, 1); p1 += __shfl_xor(p1, 1); p2 += __shfl_xor(p2, 1); p3 += __shfl_xor(p3, 1);
        p0 += __shfl_xor(p0, 2); p1 += __shfl_xor(p1, 2); p2 += __shfl_xor(p2, 2); p3 += __shfl_xor(p3, 2);
        p0 += __shfl_xor(p0, 4); p1 += __shfl_xor(p1, 4); p2 += __shfl_xor(p2, 4); p3 += __shfl_xor(p3, 4);
        p0 += __shfl_xor(p0, 8); p1 += __shfl_xor(p1, 8); p2 += __shfl_xor(p2, 8); p3 += __shfl_xor(p3, 8);
        float w0 = exp2f(p0), w1 = exp2f(p1), w2 = exp2f(p2), w3 = exp2f(p3);

        denom += w0; ax += w0 * a0.x; ay += w0 * a0.y; az += w0 * a0.z; aw += w0 * a0.w;
        if (rem > 1) { denom += w1; ax += w1 * a1.x; ay += w1 * a1.y; az += w1 * a1.z; aw += w1 * a1.w; }
        if (rem > 2) { denom += w2; ax += w2 * a2.x; ay += w2 * a2.y; az += w2 * a2.z; aw += w2 * a2.w; }
        if (rem > 3) { denom += w3; ax += w3 * a3.x; ay += w3 * a3.y; az += w3 * a3.z; aw += w3 * a3.w; }

        a0 = b0; a1 = b1; a2 = b2; a3 = b3;   // SSA rotation (regalloc coalesces)
    }

    float inv = 1.f / denom;
    float rx = ax * inv, ry = ay * inv, rz = az * inv, rw = aw * inv;
    // head mean: lanes j, j^16, j^32, j^48 share feature d
    rx += __shfl_xor(rx, 16); rx += __shfl_xor(rx, 32);
    ry += __shfl_xor(ry, 16); ry += __shfl_xor(ry, 32);
    rz += __shfl_xor(rz, 16); rz += __shfl_xor(rz, 32);
    rw += __shfl_xor(rw, 16); rw += __shfl_xor(rw, 32);

    if (lane < 16) {
        int d0 = lane * 4;
        float4 bv = *(const float4*)(gbias + d0);
        float ox = 0.25f * rx + bv.x;
        float oy = 0.25f * ry + bv.y;
        float oz = 0.25f * rz + bv.z;
        float ow = 0.25f * rw + bv.w;
        if (apply_gelu) {
            const float kk = 0.70710678118654752440f;
            ox = 0.5f * ox * (1.f + erff(ox * kk));
            oy = 0.5f * oy * (1.f + erff(oy * kk));
            oz = 0.5f * oz * (1.f + erff(oz * kk));
            ow = 0.5f * ow * (1.f + erff(ow * kk));
        }
        *(float4*)(xout + (size_t)n * 64 + d0) = make_float4(ox, oy, oz, ow);
    }
}

// ---------------------------------------------------------------------------
// Global mean pool (batch sorted) + classifier. Block per graph, 64 threads.
// ---------------------------------------------------------------------------
__global__ __launch_bounds__(64) void pool_kernel(
        const float* __restrict__ x, const int* __restrict__ batch,
        const float* __restrict__ Wc, const float* __restrict__ bc,
        float* __restrict__ out, int N, int G) {
    __shared__ float pooled[64];
    int g = blockIdx.x, t = threadIdx.x;
    int lo = 0, hi = N;
    while (lo < hi) { int mid = (lo + hi) >> 1; if (batch[mid] < g) lo = mid + 1; else hi = mid; }
    int beg = lo;
    hi = N;
    while (lo < hi) { int mid = (lo + hi) >> 1; if (batch[mid] < g + 1) lo = mid + 1; else hi = mid; }
    int end = lo;

    float acc = 0.f;
    for (int n = beg; n < end; ++n) acc += x[(size_t)n * 64 + t];
    int cnt = end - beg;
    pooled[t] = (cnt > 0) ? acc / (float)cnt : 0.f;
    __syncthreads();
    if (t < 10) {
        float o = bc[t];
        for (int d = 0; d < 64; ++d) o += pooled[d] * Wc[d * 10 + t];
        out[(size_t)g * 10 + t] = o;
    }
}

// ---------------------------------------------------------------------------
extern "C" void kernel_launch(void* const* d_in, const int* in_sizes, int n_in,
                              void* d_out, int out_size, void* d_ws, size_t ws_size,
                              hipStream_t stream) {
    const int*   feat  = (const int*)d_in[0];
    const int*   edges = (const int*)d_in[1];
    const int*   batch = (const int*)d_in[2];
    const float* emb   = (const float*)d_in[3];
    const float* Wl    = (const float*)d_in[4];
    const float* bl    = (const float*)d_in[5];
    const float* Wr    = (const float*)d_in[6];
    const float* br    = (const float*)d_in[7];
    const float* att   = (const float*)d_in[8];
    const float* gb    = (const float*)d_in[9];
    const float* Wc    = (const float*)d_in[10];
    const float* bc    = (const float*)d_in[11];
    float* out = (float*)d_out;

    const int N = in_sizes[2];
    const int E = in_sizes[1] / 2;
    const int G = out_size / 10;

    char* ws = (char*)d_ws;
    size_t off = 0;
    auto alloc = [&](size_t bytes) -> char* {
        char* p = ws + off;
        off = (off + bytes + 255) & ~(size_t)255;
        return p;
    };
    float* x         = (float*)alloc((size_t)N * 64 * 4);
    float* xl        = (float*)alloc((size_t)N * 256 * 4);
    float* xr        = (float*)alloc((size_t)N * 256 * 4);
    int*   counts    = (int*)alloc((size_t)N * 4);
    int*   csr_off   = (int*)alloc((size_t)(N + 1) * 4);
    int*   cursor    = (int*)alloc((size_t)N * 4);
    int*   csr_src   = (int*)alloc((size_t)(E + N) * 4);
    int*   blockSums = (int*)alloc(256 * 4);

    const int* srcv = edges;
    const int* dstv = edges + E;

    // 1) zero counts, then fused embed + histogram
    hipMemsetAsync(counts, 0, (size_t)N * 4, stream);
    hipLaunchKernelGGL(embed_kernel, dim3((N + 3) / 4), dim3(256), 0, stream,
                       feat, emb, dstv, counts, x, N, E);

    // 2) CSR by destination, self-loop at each segment head (+1 in scan)
    int nb = (N + 1023) / 1024;
    hipLaunchKernelGGL(scan_block_kernel, dim3(nb), dim3(256), 0, stream, counts, csr_off, blockSums, N);
    hipLaunchKernelGGL(scan_sums_kernel, dim3(1), dim3(64), 0, stream, blockSums, nb);
    hipLaunchKernelGGL(finalize_kernel, dim3((N + 255) / 256), dim3(256), 0, stream,
                       csr_off, blockSums, cursor, csr_src, N, E + N);
    hipLaunchKernelGGL(scatter_kernel, dim3((E + 255) / 256), dim3(256), 0, stream, srcv, dstv, cursor, csr_src, E);

    // 3) GATv2 layers
    for (int l = 0; l < 3; ++l) {
        hipLaunchKernelGGL(gemm_kernel, dim3((N + 63) / 64, 4), dim3(256), 0, stream,
                           x, Wl + (size_t)l * 64 * 256, Wr + (size_t)l * 64 * 256,
                           bl + l * 256, br + l * 256, xl, xr, N);
        hipLaunchKernelGGL(agg_kernel, dim3((N + 3) / 4), dim3(256), 0, stream,
                           xl, xr, csr_off, csr_src, att + l * 256, gb + l * 64,
                           x, N, (l < 2) ? 1 : 0);
    }

    // 4) pool + classify
    hipLaunchKernelGGL(pool_kernel, dim3(G), dim3(64), 0, stream, x, batch, Wc, bc, out, N, G);
}

// Round 5
// 537.726 us; speedup vs baseline: 1.0224x; 1.0224x over previous
//
#include <hip/hip_runtime.h>
#include <math.h>

#define NEG_SLOPE 0.2f
#define LOG2E 1.44269504088896340736f

#if __has_builtin(__builtin_amdgcn_exp2f)
#define EXP2(x) __builtin_amdgcn_exp2f(x)
#else
#define EXP2(x) exp2f(x)
#endif

// in-wave butterfly add via DPP (single VALU op pair, no DS pipe):
// xor1 = quad_perm[1,0,3,2]=0xB1 ; xor2 = quad_perm[2,3,0,1]=0x4E ;
// xor4 == row_half_mirror (0x141) given quad-constant values ;
// xor8 == row_mirror (0x140) given oct-constant values.
#define DPP_ADD(p, ctrl) \
    p += __int_as_float(__builtin_amdgcn_update_dpp(0, __float_as_int(p), ctrl, 0xf, 0xf, true))

// ---------------------------------------------------------------------------
// AtomEncoder + edge histogram (fused). One wave per node; counts[] gets raw
// in-degree (pre-zeroed by memsetAsync).
// ---------------------------------------------------------------------------
__global__ __launch_bounds__(256) void embed_kernel(
        const int* __restrict__ feat, const float* __restrict__ emb,
        const int* __restrict__ dstE, int* __restrict__ counts,
        float* __restrict__ x, int N, int E) {
    int gid = blockIdx.x * 256 + threadIdx.x;
    if (gid < E) atomicAdd(&counts[dstE[gid]], 1);

    const int offs[9] = {0, 119, 124, 136, 148, 158, 164, 170, 172};
    int sub  = threadIdx.x >> 6;
    int lane = threadIdx.x & 63;
    int n = __builtin_amdgcn_readfirstlane(blockIdx.x * 4 + sub);
    if (n >= N) return;
    float s = 0.f;
#pragma unroll
    for (int j = 0; j < 9; ++j) {
        int idx = feat[n * 9 + j] + offs[j];
        s += emb[idx * 64 + lane];
    }
    x[(size_t)n * 64 + lane] = s;
}

// ---------------------------------------------------------------------------
// Dual GEMM: xl = x @ Wl + bl ; xr = x @ Wr + br. Tile 64x128, BK=32, 256 thr,
// 8 contiguous rows x 4 cols per thread.
// ---------------------------------------------------------------------------
__global__ __launch_bounds__(256) void gemm_kernel(
        const float* __restrict__ x,
        const float* __restrict__ Wl, const float* __restrict__ Wr,
        const float* __restrict__ bl, const float* __restrict__ br,
        float* __restrict__ xl, float* __restrict__ xr, int N) {
    __shared__ __align__(16) float As[32][64];
    __shared__ __align__(16) float Bs[32][128];
    int t  = threadIdx.x;
    int m0 = blockIdx.x * 64;
    int ct = blockIdx.y;
    const float* B    = (ct < 2) ? Wl : Wr;
    const float* bias = (ct < 2) ? bl : br;
    float*       out  = (ct < 2) ? xl : xr;
    int cb = (ct & 1) * 128;

    int m   = t & 63;
    int kq0 = t >> 6;
    int row = m0 + m;
    int c4  = t & 31;
    int k0  = t >> 5;
    int tx  = t & 31;
    int ty  = t >> 5;

    float4 acc[8];
#pragma unroll
    for (int i = 0; i < 8; ++i) acc[i] = make_float4(0.f, 0.f, 0.f, 0.f);

#pragma unroll
    for (int kb = 0; kb < 2; ++kb) {
        float4 a0 = make_float4(0.f, 0.f, 0.f, 0.f), a1 = a0;
        if (row < N) {
            a0 = *(const float4*)(x + (size_t)row * 64 + (kb * 8 + kq0) * 4);
            a1 = *(const float4*)(x + (size_t)row * 64 + (kb * 8 + kq0 + 4) * 4);
        }
        float4 bv[4];
#pragma unroll
        for (int j = 0; j < 4; ++j) {
            int k = kb * 32 + k0 + j * 8;
            bv[j] = *(const float4*)(B + (size_t)k * 256 + cb + c4 * 4);
        }
        if (kb) __syncthreads();
        As[kq0 * 4 + 0][m] = a0.x; As[kq0 * 4 + 1][m] = a0.y;
        As[kq0 * 4 + 2][m] = a0.z; As[kq0 * 4 + 3][m] = a0.w;
        As[(kq0 + 4) * 4 + 0][m] = a1.x; As[(kq0 + 4) * 4 + 1][m] = a1.y;
        As[(kq0 + 4) * 4 + 2][m] = a1.z; As[(kq0 + 4) * 4 + 3][m] = a1.w;
#pragma unroll
        for (int j = 0; j < 4; ++j)
            *(float4*)(&Bs[k0 + j * 8][c4 * 4]) = bv[j];
        __syncthreads();

#pragma unroll 8
        for (int k = 0; k < 32; ++k) {
            float4 b   = *(const float4*)(&Bs[k][tx * 4]);
            float4 alo = *(const float4*)(&As[k][ty * 8]);
            float4 ahi = *(const float4*)(&As[k][ty * 8 + 4]);
            acc[0].x += alo.x * b.x; acc[0].y += alo.x * b.y; acc[0].z += alo.x * b.z; acc[0].w += alo.x * b.w;
            acc[1].x += alo.y * b.x; acc[1].y += alo.y * b.y; acc[1].z += alo.y * b.z; acc[1].w += alo.y * b.w;
            acc[2].x += alo.z * b.x; acc[2].y += alo.z * b.y; acc[2].z += alo.z * b.z; acc[2].w += alo.z * b.w;
            acc[3].x += alo.w * b.x; acc[3].y += alo.w * b.y; acc[3].z += alo.w * b.z; acc[3].w += alo.w * b.w;
            acc[4].x += ahi.x * b.x; acc[4].y += ahi.x * b.y; acc[4].z += ahi.x * b.z; acc[4].w += ahi.x * b.w;
            acc[5].x += ahi.y * b.x; acc[5].y += ahi.y * b.y; acc[5].z += ahi.y * b.z; acc[5].w += ahi.y * b.w;
            acc[6].x += ahi.z * b.x; acc[6].y += ahi.z * b.y; acc[6].z += ahi.z * b.z; acc[6].w += ahi.z * b.w;
            acc[7].x += ahi.w * b.x; acc[7].y += ahi.w * b.y; acc[7].z += ahi.w * b.z; acc[7].w += ahi.w * b.w;
        }
    }

    float4 bb = *(const float4*)(bias + cb + tx * 4);
#pragma unroll
    for (int i = 0; i < 8; ++i) {
        int r = m0 + ty * 8 + i;
        if (r < N) {
            float4 o = acc[i];
            o.x += bb.x; o.y += bb.y; o.z += bb.z; o.w += bb.w;
            *(float4*)(out + (size_t)r * 256 + cb + tx * 4) = o;
        }
    }
}

// ---------------------------------------------------------------------------
// CSR build, PADDED: each node's segment = self loop + indeg edges, rounded up
// to a multiple of 4 slots (pad slots hold the node id -> valid dup rows).
// counts[] keeps raw indeg (agg uses it to zero pad weights).
// ---------------------------------------------------------------------------
__global__ void scan_block_kernel(const int* __restrict__ counts, int* __restrict__ excl,
                                  int* __restrict__ blockSums, int N) {
    __shared__ int lds[256];
    int b = blockIdx.x, t = threadIdx.x;
    int base = b * 1024 + t * 4;
    int v0 = (base + 0 < N) ? ((counts[base + 0] + 4) & ~3) : 0;  // pad(deg+1,4)
    int v1 = (base + 1 < N) ? ((counts[base + 1] + 4) & ~3) : 0;
    int v2 = (base + 2 < N) ? ((counts[base + 2] + 4) & ~3) : 0;
    int v3 = (base + 3 < N) ? ((counts[base + 3] + 4) & ~3) : 0;
    int s = v0 + v1 + v2 + v3;
    lds[t] = s;
    __syncthreads();
    for (int off = 1; off < 256; off <<= 1) {
        int add = (t >= off) ? lds[t - off] : 0;
        __syncthreads();
        lds[t] += add;
        __syncthreads();
    }
    int run = lds[t] - s;
    if (base + 0 < N) excl[base + 0] = run; run += v0;
    if (base + 1 < N) excl[base + 1] = run; run += v1;
    if (base + 2 < N) excl[base + 2] = run; run += v2;
    if (base + 3 < N) excl[base + 3] = run;
    if (t == 255) blockSums[b] = lds[255];
}

__global__ void scan_sums_kernel(int* __restrict__ blockSums, int nb) {
    __shared__ int lds[64];
    int t = threadIdx.x;  // nb <= 64 (N <= 65536)
    int v = (t < nb) ? blockSums[t] : 0;
    lds[t] = v;
    __syncthreads();
    for (int off = 1; off < 64; off <<= 1) {
        int add = (t >= off) ? lds[t - off] : 0;
        __syncthreads();
        lds[t] += add;
        __syncthreads();
    }
    if (t < nb) blockSums[t] = lds[t] - v;
}

__global__ void finalize_kernel(int* __restrict__ csr_off, const int* __restrict__ blockSums,
                                int* __restrict__ cursor, int* __restrict__ csr_src,
                                const int* __restrict__ counts, int N) {
    int i = blockIdx.x * 256 + threadIdx.x;
    if (i < N) {
        int v = csr_off[i] + blockSums[i >> 10];
        csr_off[i] = v;
        int deg  = counts[i];
        int plen = (deg + 4) & ~3;
        csr_src[v] = i;                                   // self loop at head
        for (int k = deg + 1; k < plen; ++k) csr_src[v + k] = i;  // pad fill
        cursor[i] = v + 1;
        if (i == N - 1) csr_off[N] = v + plen;
    }
}

__global__ void scatter_kernel(const int* __restrict__ src, const int* __restrict__ dst,
                               int* __restrict__ cursor, int* __restrict__ csr_src, int E) {
    int e = blockIdx.x * 256 + threadIdx.x;
    if (e < E) {
        int pos = atomicAdd(&cursor[dst[e]], 1);
        csr_src[pos] = src[e];
    }
}

// ---------------------------------------------------------------------------
// GATv2 aggregation v2: one wave per FOUR consecutive dst nodes. Their padded
// CSR segments form one contiguous, group-of-4-aligned edge stream, so the
// gather pipeline (index s_load_dwordx4 -> 4x global row gathers) never drains
// across node boundaries; csr_off/counts/xr-rows for all 4 nodes prefetched
// once. Head reduction via DPP adds (no DS pipe). Pad-slot weights zeroed by
// wave-uniform compares against the real count.
// ---------------------------------------------------------------------------
__global__ __launch_bounds__(256) void agg_kernel(
        const float* __restrict__ xl, const float* __restrict__ xr,
        const int* __restrict__ po,      // padded csr offsets [N+1]
        const int* __restrict__ csr_src, // padded [po[N]]
        const int* __restrict__ counts,  // raw indeg [N]
        const float* __restrict__ att,   // [4*64] this layer (pre-scaled below)
        const float* __restrict__ gbias, // [64] this layer
        float* __restrict__ xout, int N, int apply_gelu) {
    int wave = threadIdx.x >> 6;
    int lane = threadIdx.x & 63;
    int n0 = __builtin_amdgcn_readfirstlane((blockIdx.x * 4 + wave) * 4);
    if (n0 >= N) return;   // N % 4 == 0 for this problem; whole wave exits

    float4 att4 = ((const float4*)att)[lane];
    att4.x *= LOG2E; att4.y *= LOG2E; att4.z *= LOG2E; att4.w *= LOG2E;

    // wave-uniform metadata (scalar loads)
    int4 pv = *(const int4*)(po + n0);
    int  p4 = po[n0 + 4];
    int4 cv = *(const int4*)(counts + n0);

    // prefetch the 4 target rows
    const float* __restrict__ xrl = xr + lane * 4;
    float4 xr0 = *(const float4*)(xrl + (size_t)(n0 + 0) * 256);
    float4 xr1 = *(const float4*)(xrl + (size_t)(n0 + 1) * 256);
    float4 xr2 = *(const float4*)(xrl + (size_t)(n0 + 2) * 256);
    float4 xr3 = *(const float4*)(xrl + (size_t)(n0 + 3) * 256);

    const float* __restrict__ xlp = xl + lane * 4;
    int lastPos = p4 - 4;            // last group start in this wave's range

    // pipeline state: a* = current group rows, jv = next group's indices
    int4 iv = *(const int4*)(csr_src + pv.x);
    float4 a0 = *(const float4*)(xlp + (size_t)iv.x * 256);
    float4 a1 = *(const float4*)(xlp + (size_t)iv.y * 256);
    float4 a2 = *(const float4*)(xlp + (size_t)iv.z * 256);
    float4 a3 = *(const float4*)(xlp + (size_t)iv.w * 256);
    int4 jv = *(const int4*)(csr_src + min(pv.x + 4, lastPos));
    int nextPos = pv.x + 8;

    float ax = 0.f, ay = 0.f, az = 0.f, aw = 0.f, denom = 0.f;

    auto logit = [&](const float4& v, const float4& r) -> float {
        float s0 = v.x + r.x, s1 = v.y + r.y, s2 = v.z + r.z, s3 = v.w + r.w;
        float t0 = fmaxf(s0, NEG_SLOPE * s0);
        float t1 = fmaxf(s1, NEG_SLOPE * s1);
        float t2 = fmaxf(s2, NEG_SLOPE * s2);
        float t3 = fmaxf(s3, NEG_SLOPE * s3);
        return t0 * att4.x + t1 * att4.y + t2 * att4.z + t3 * att4.w;
    };

    auto step = [&](const float4& xr4, int kbase, int mrc) {
        // prefetch next group (rows + next-next indices)
        float4 b0 = *(const float4*)(xlp + (size_t)jv.x * 256);
        float4 b1 = *(const float4*)(xlp + (size_t)jv.y * 256);
        float4 b2 = *(const float4*)(xlp + (size_t)jv.z * 256);
        float4 b3 = *(const float4*)(xlp + (size_t)jv.w * 256);
        int4 jv2 = *(const int4*)(csr_src + min(nextPos, lastPos));
        nextPos += 4;

        float p0 = logit(a0, xr4), p1 = logit(a1, xr4), p2 = logit(a2, xr4), p3 = logit(a3, xr4);
        DPP_ADD(p0, 0xB1);  DPP_ADD(p1, 0xB1);  DPP_ADD(p2, 0xB1);  DPP_ADD(p3, 0xB1);
        DPP_ADD(p0, 0x4E);  DPP_ADD(p1, 0x4E);  DPP_ADD(p2, 0x4E);  DPP_ADD(p3, 0x4E);
        DPP_ADD(p0, 0x141); DPP_ADD(p1, 0x141); DPP_ADD(p2, 0x141); DPP_ADD(p3, 0x141);
        DPP_ADD(p0, 0x140); DPP_ADD(p1, 0x140); DPP_ADD(p2, 0x140); DPP_ADD(p3, 0x140);
        float w0 = EXP2(p0), w1 = EXP2(p1), w2 = EXP2(p2), w3 = EXP2(p3);
        // zero pad slots (kbase < mrc always holds for slot 0)
        if (kbase + 1 >= mrc) w1 = 0.f;
        if (kbase + 2 >= mrc) w2 = 0.f;
        if (kbase + 3 >= mrc) w3 = 0.f;

        denom += (w0 + w1) + (w2 + w3);
        ax += w0 * a0.x + w1 * a1.x + w2 * a2.x + w3 * a3.x;
        ay += w0 * a0.y + w1 * a1.y + w2 * a2.y + w3 * a3.y;
        az += w0 * a0.z + w1 * a1.z + w2 * a2.z + w3 * a3.z;
        aw += w0 * a0.w + w1 * a1.w + w2 * a2.w + w3 * a3.w;

        a0 = b0; a1 = b1; a2 = b2; a3 = b3; jv = jv2;
    };

    auto finish = [&](int n) {
        float inv = 1.f / denom;
        float rx = ax * inv, ry = ay * inv, rz = az * inv, rw = aw * inv;
        rx += __shfl_xor(rx, 16); rx += __shfl_xor(rx, 32);
        ry += __shfl_xor(ry, 16); ry += __shfl_xor(ry, 32);
        rz += __shfl_xor(rz, 16); rz += __shfl_xor(rz, 32);
        rw += __shfl_xor(rw, 16); rw += __shfl_xor(rw, 32);
        if (lane < 16) {
            int d0 = lane * 4;
            float4 bv = *(const float4*)(gbias + d0);
            float ox = 0.25f * rx + bv.x;
            float oy = 0.25f * ry + bv.y;
            float oz = 0.25f * rz + bv.z;
            float ow = 0.25f * rw + bv.w;
            if (apply_gelu) {
                const float kk = 0.70710678118654752440f;
                ox = 0.5f * ox * (1.f + erff(ox * kk));
                oy = 0.5f * oy * (1.f + erff(oy * kk));
                oz = 0.5f * oz * (1.f + erff(oz * kk));
                ow = 0.5f * ow * (1.f + erff(ow * kk));
            }
            *(float4*)(xout + (size_t)n * 64 + d0) = make_float4(ox, oy, oz, ow);
        }
        ax = ay = az = aw = denom = 0.f;
    };

    { int gsz = (pv.y - pv.x) >> 2, mrc = cv.x + 1;
      for (int g = 0; g < gsz; ++g) step(xr0, g * 4, mrc);
      finish(n0 + 0); }
    { int gsz = (pv.z - pv.y) >> 2, mrc = cv.y + 1;
      for (int g = 0; g < gsz; ++g) step(xr1, g * 4, mrc);
      finish(n0 + 1); }
    { int gsz = (pv.w - pv.z) >> 2, mrc = cv.z + 1;
      for (int g = 0; g < gsz; ++g) step(xr2, g * 4, mrc);
      finish(n0 + 2); }
    { int gsz = (p4 - pv.w) >> 2, mrc = cv.w + 1;
      for (int g = 0; g < gsz; ++g) step(xr3, g * 4, mrc);
      finish(n0 + 3); }
}

// ---------------------------------------------------------------------------
// Global mean pool (batch sorted) + classifier. Block per graph, 256 threads
// (4 rows in parallel -> 4x the outstanding loads of the old 64-thread loop).
// Deterministic: fixed row->sub assignment, ordered partial combine.
// ---------------------------------------------------------------------------
__global__ __launch_bounds__(256) void pool_kernel(
        const float* __restrict__ x, const int* __restrict__ batch,
        const float* __restrict__ Wc, const float* __restrict__ bc,
        float* __restrict__ out, int N, int G) {
    __shared__ float part[4][64];
    __shared__ float pooled[64];
    int g = blockIdx.x, t = threadIdx.x;
    int sub = t >> 6, lane = t & 63;
    int lo = 0, hi = N;
    while (lo < hi) { int mid = (lo + hi) >> 1; if (batch[mid] < g) lo = mid + 1; else hi = mid; }
    int beg = lo;
    hi = N;
    while (lo < hi) { int mid = (lo + hi) >> 1; if (batch[mid] < g + 1) lo = mid + 1; else hi = mid; }
    int end = lo;

    float acc = 0.f;
    for (int n = beg + sub; n < end; n += 4) acc += x[(size_t)n * 64 + lane];
    part[sub][lane] = acc;
    __syncthreads();
    if (t < 64) {
        float s = (part[0][t] + part[1][t]) + (part[2][t] + part[3][t]);
        int cnt = end - beg;
        pooled[t] = (cnt > 0) ? s / (float)cnt : 0.f;
    }
    __syncthreads();
    if (t < 10) {
        float o = bc[t];
        for (int d = 0; d < 64; ++d) o += pooled[d] * Wc[d * 10 + t];
        out[(size_t)g * 10 + t] = o;
    }
}

// ---------------------------------------------------------------------------
extern "C" void kernel_launch(void* const* d_in, const int* in_sizes, int n_in,
                              void* d_out, int out_size, void* d_ws, size_t ws_size,
                              hipStream_t stream) {
    const int*   feat  = (const int*)d_in[0];
    const int*   edges = (const int*)d_in[1];
    const int*   batch = (const int*)d_in[2];
    const float* emb   = (const float*)d_in[3];
    const float* Wl    = (const float*)d_in[4];
    const float* bl    = (const float*)d_in[5];
    const float* Wr    = (const float*)d_in[6];
    const float* br    = (const float*)d_in[7];
    const float* att   = (const float*)d_in[8];
    const float* gb    = (const float*)d_in[9];
    const float* Wc    = (const float*)d_in[10];
    const float* bc    = (const float*)d_in[11];
    float* out = (float*)d_out;

    const int N = in_sizes[2];
    const int E = in_sizes[1] / 2;
    const int G = out_size / 10;

    char* ws = (char*)d_ws;
    size_t off = 0;
    auto alloc = [&](size_t bytes) -> char* {
        char* p = ws + off;
        off = (off + bytes + 255) & ~(size_t)255;
        return p;
    };
    float* x         = (float*)alloc((size_t)N * 64 * 4);
    float* xl        = (float*)alloc((size_t)N * 256 * 4);
    float* xr        = (float*)alloc((size_t)N * 256 * 4);
    int*   counts    = (int*)alloc((size_t)N * 4);
    int*   csr_off   = (int*)alloc((size_t)(N + 8) * 4);
    int*   cursor    = (int*)alloc((size_t)N * 4);
    int*   csr_src   = (int*)alloc((size_t)(E + 4 * N + 64) * 4);  // padded
    int*   blockSums = (int*)alloc(256 * 4);

    const int* srcv = edges;
    const int* dstv = edges + E;

    // 1) zero counts, fused embed + histogram
    hipMemsetAsync(counts, 0, (size_t)N * 4, stream);
    hipLaunchKernelGGL(embed_kernel, dim3((N + 3) / 4), dim3(256), 0, stream,
                       feat, emb, dstv, counts, x, N, E);

    // 2) padded CSR by destination
    int nb = (N + 1023) / 1024;
    hipLaunchKernelGGL(scan_block_kernel, dim3(nb), dim3(256), 0, stream, counts, csr_off, blockSums, N);
    hipLaunchKernelGGL(scan_sums_kernel, dim3(1), dim3(64), 0, stream, blockSums, nb);
    hipLaunchKernelGGL(finalize_kernel, dim3((N + 255) / 256), dim3(256), 0, stream,
                       csr_off, blockSums, cursor, csr_src, counts, N);
    hipLaunchKernelGGL(scatter_kernel, dim3((E + 255) / 256), dim3(256), 0, stream, srcv, dstv, cursor, csr_src, E);

    // 3) GATv2 layers
    int aggBlocks = (N + 15) / 16;   // 4 waves/block, 4 nodes/wave
    for (int l = 0; l < 3; ++l) {
        hipLaunchKernelGGL(gemm_kernel, dim3((N + 63) / 64, 4), dim3(256), 0, stream,
                           x, Wl + (size_t)l * 64 * 256, Wr + (size_t)l * 64 * 256,
                           bl + l * 256, br + l * 256, xl, xr, N);
        hipLaunchKernelGGL(agg_kernel, dim3(aggBlocks), dim3(256), 0, stream,
                           xl, xr, csr_off, csr_src, counts, att + l * 256, gb + l * 64,
                           x, N, (l < 2) ? 1 : 0);
    }

    // 4) pool + classify
    hipLaunchKernelGGL(pool_kernel, dim3(G), dim3(256), 0, stream, x, batch, Wc, bc, out, N, G);
}

// Round 6
// 525.657 us; speedup vs baseline: 1.0459x; 1.0230x over previous
//
#include <hip/hip_runtime.h>
#include <math.h>

#define NEG_SLOPE 0.2f
#define LOG2E 1.44269504088896340736f

#if __has_builtin(__builtin_amdgcn_exp2f)
#define EXP2(x) __builtin_amdgcn_exp2f(x)
#else
#define EXP2(x) exp2f(x)
#endif

// in-wave butterfly add via DPP (plain VALU, no DS pipe / no address setup):
// xor1 = quad_perm[1,0,3,2]=0xB1 ; xor2 = quad_perm[2,3,0,1]=0x4E ;
// xor4 == row_half_mirror (0x141) on quad-constant values ;
// xor8 == row_mirror (0x140) on oct-constant values.  (validated in R5)
#define DPP_ADD(p, ctrl) \
    p += __int_as_float(__builtin_amdgcn_update_dpp(0, __float_as_int(p), ctrl, 0xf, 0xf, true))

// ---------------------------------------------------------------------------
// AtomEncoder + edge histogram (fused). One wave per node; counts[] gets raw
// in-degree (pre-zeroed by memsetAsync); self-loop "+1" folded into the scan.
// ---------------------------------------------------------------------------
__global__ __launch_bounds__(256) void embed_kernel(
        const int* __restrict__ feat, const float* __restrict__ emb,
        const int* __restrict__ dstE, int* __restrict__ counts,
        float* __restrict__ x, int N, int E) {
    int gid = blockIdx.x * 256 + threadIdx.x;
    if (gid < E) atomicAdd(&counts[dstE[gid]], 1);

    const int offs[9] = {0, 119, 124, 136, 148, 158, 164, 170, 172};
    int sub  = threadIdx.x >> 6;
    int lane = threadIdx.x & 63;
    int n = __builtin_amdgcn_readfirstlane(blockIdx.x * 4 + sub);
    if (n >= N) return;
    float s = 0.f;
#pragma unroll
    for (int j = 0; j < 9; ++j) {
        int idx = feat[n * 9 + j] + offs[j];
        s += emb[idx * 64 + lane];
    }
    x[(size_t)n * 64 + lane] = s;
}

// ---------------------------------------------------------------------------
// Dual GEMM: xl = x @ Wl + bl ; xr = x @ Wr + br. Tile 64x128, BK=32, 256 thr,
// 8 contiguous rows x 4 cols per thread. (unchanged this round — need its
// counters in the top-5 before touching it)
// ---------------------------------------------------------------------------
__global__ __launch_bounds__(256) void gemm_kernel(
        const float* __restrict__ x,
        const float* __restrict__ Wl, const float* __restrict__ Wr,
        const float* __restrict__ bl, const float* __restrict__ br,
        float* __restrict__ xl, float* __restrict__ xr, int N) {
    __shared__ __align__(16) float As[32][64];
    __shared__ __align__(16) float Bs[32][128];
    int t  = threadIdx.x;
    int m0 = blockIdx.x * 64;
    int ct = blockIdx.y;
    const float* B    = (ct < 2) ? Wl : Wr;
    const float* bias = (ct < 2) ? bl : br;
    float*       out  = (ct < 2) ? xl : xr;
    int cb = (ct & 1) * 128;

    int m   = t & 63;
    int kq0 = t >> 6;
    int row = m0 + m;
    int c4  = t & 31;
    int k0  = t >> 5;
    int tx  = t & 31;
    int ty  = t >> 5;

    float4 acc[8];
#pragma unroll
    for (int i = 0; i < 8; ++i) acc[i] = make_float4(0.f, 0.f, 0.f, 0.f);

#pragma unroll
    for (int kb = 0; kb < 2; ++kb) {
        float4 a0 = make_float4(0.f, 0.f, 0.f, 0.f), a1 = a0;
        if (row < N) {
            a0 = *(const float4*)(x + (size_t)row * 64 + (kb * 8 + kq0) * 4);
            a1 = *(const float4*)(x + (size_t)row * 64 + (kb * 8 + kq0 + 4) * 4);
        }
        float4 bv[4];
#pragma unroll
        for (int j = 0; j < 4; ++j) {
            int k = kb * 32 + k0 + j * 8;
            bv[j] = *(const float4*)(B + (size_t)k * 256 + cb + c4 * 4);
        }
        if (kb) __syncthreads();
        As[kq0 * 4 + 0][m] = a0.x; As[kq0 * 4 + 1][m] = a0.y;
        As[kq0 * 4 + 2][m] = a0.z; As[kq0 * 4 + 3][m] = a0.w;
        As[(kq0 + 4) * 4 + 0][m] = a1.x; As[(kq0 + 4) * 4 + 1][m] = a1.y;
        As[(kq0 + 4) * 4 + 2][m] = a1.z; As[(kq0 + 4) * 4 + 3][m] = a1.w;
#pragma unroll
        for (int j = 0; j < 4; ++j)
            *(float4*)(&Bs[k0 + j * 8][c4 * 4]) = bv[j];
        __syncthreads();

#pragma unroll 8
        for (int k = 0; k < 32; ++k) {
            float4 b   = *(const float4*)(&Bs[k][tx * 4]);
            float4 alo = *(const float4*)(&As[k][ty * 8]);
            float4 ahi = *(const float4*)(&As[k][ty * 8 + 4]);
            acc[0].x += alo.x * b.x; acc[0].y += alo.x * b.y; acc[0].z += alo.x * b.z; acc[0].w += alo.x * b.w;
            acc[1].x += alo.y * b.x; acc[1].y += alo.y * b.y; acc[1].z += alo.y * b.z; acc[1].w += alo.y * b.w;
            acc[2].x += alo.z * b.x; acc[2].y += alo.z * b.y; acc[2].z += alo.z * b.z; acc[2].w += alo.z * b.w;
            acc[3].x += alo.w * b.x; acc[3].y += alo.w * b.y; acc[3].z += alo.w * b.z; acc[3].w += alo.w * b.w;
            acc[4].x += ahi.x * b.x; acc[4].y += ahi.x * b.y; acc[4].z += ahi.x * b.z; acc[4].w += ahi.x * b.w;
            acc[5].x += ahi.y * b.x; acc[5].y += ahi.y * b.y; acc[5].z += ahi.y * b.z; acc[5].w += ahi.y * b.w;
            acc[6].x += ahi.z * b.x; acc[6].y += ahi.z * b.y; acc[6].z += ahi.z * b.z; acc[6].w += ahi.z * b.w;
            acc[7].x += ahi.w * b.x; acc[7].y += ahi.w * b.y; acc[7].z += ahi.w * b.z; acc[7].w += ahi.w * b.w;
        }
    }

    float4 bb = *(const float4*)(bias + cb + tx * 4);
#pragma unroll
    for (int i = 0; i < 8; ++i) {
        int r = m0 + ty * 8 + i;
        if (r < N) {
            float4 o = acc[i];
            o.x += bb.x; o.y += bb.y; o.z += bb.z; o.w += bb.w;
            *(float4*)(out + (size_t)r * 256 + cb + tx * 4) = o;
        }
    }
}

// ---------------------------------------------------------------------------
// CSR build (unpadded; self loop at each segment head, +1 folded into scan)
// ---------------------------------------------------------------------------
__global__ void scan_block_kernel(const int* __restrict__ counts, int* __restrict__ excl,
                                  int* __restrict__ blockSums, int N) {
    __shared__ int lds[256];
    int b = blockIdx.x, t = threadIdx.x;
    int base = b * 1024 + t * 4;
    int v0 = (base + 0 < N) ? counts[base + 0] + 1 : 0;   // +1 = self loop
    int v1 = (base + 1 < N) ? counts[base + 1] + 1 : 0;
    int v2 = (base + 2 < N) ? counts[base + 2] + 1 : 0;
    int v3 = (base + 3 < N) ? counts[base + 3] + 1 : 0;
    int s = v0 + v1 + v2 + v3;
    lds[t] = s;
    __syncthreads();
    for (int off = 1; off < 256; off <<= 1) {
        int add = (t >= off) ? lds[t - off] : 0;
        __syncthreads();
        lds[t] += add;
        __syncthreads();
    }
    int run = lds[t] - s;
    if (base + 0 < N) excl[base + 0] = run; run += v0;
    if (base + 1 < N) excl[base + 1] = run; run += v1;
    if (base + 2 < N) excl[base + 2] = run; run += v2;
    if (base + 3 < N) excl[base + 3] = run;
    if (t == 255) blockSums[b] = lds[255];
}

__global__ void scan_sums_kernel(int* __restrict__ blockSums, int nb) {
    __shared__ int lds[64];
    int t = threadIdx.x;  // nb <= 64 (N <= 65536)
    int v = (t < nb) ? blockSums[t] : 0;
    lds[t] = v;
    __syncthreads();
    for (int off = 1; off < 64; off <<= 1) {
        int add = (t >= off) ? lds[t - off] : 0;
        __syncthreads();
        lds[t] += add;
        __syncthreads();
    }
    if (t < nb) blockSums[t] = lds[t] - v;
}

__global__ void finalize_kernel(int* __restrict__ csr_off, const int* __restrict__ blockSums,
                                int* __restrict__ cursor, int* __restrict__ csr_src,
                                int N, int total) {
    int i = blockIdx.x * 256 + threadIdx.x;
    if (i < N) {
        int v = csr_off[i] + blockSums[i >> 10];
        csr_off[i] = v;
        csr_src[v] = i;    // self loop at segment head
        cursor[i]  = v + 1;
    }
    if (i == 0) csr_off[N] = total;
}

__global__ void scatter_kernel(const int* __restrict__ src, const int* __restrict__ dst,
                               int* __restrict__ cursor, int* __restrict__ csr_src, int E) {
    int e = blockIdx.x * 256 + threadIdx.x;
    if (e < E) {
        int pos = atomicAdd(&cursor[dst[e]], 1);
        csr_src[pos] = src[e];
    }
}

// ---------------------------------------------------------------------------
// GATv2 aggregation v3: ONE wave per dst node (best measured balance), n
// wave-uniform via readfirstlane (metadata/index reads -> scalar pipe).
// 4-edge groups, 1-group-ahead row prefetch + 2-ahead index prefetch,
// unconditional clamped loads (dup rows L1-hot). Head reduction via DPP adds
// (no DS pipe). Tail handled by zeroing weights (cndmask, branchless).
// ---------------------------------------------------------------------------
__global__ __launch_bounds__(256) void agg_kernel(
        const float* __restrict__ xl, const float* __restrict__ xr,
        const int* __restrict__ csr_off, const int* __restrict__ csr_src,
        const float* __restrict__ att,   // [4*64] this layer
        const float* __restrict__ gbias, // [64] this layer
        float* __restrict__ xout, int N, int apply_gelu) {
    int wave = threadIdx.x >> 6;
    int lane = threadIdx.x & 63;
    int n = __builtin_amdgcn_readfirstlane(blockIdx.x * 4 + wave);
    if (n >= N) return;

    float4 att4 = ((const float4*)att)[lane];
    att4.x *= LOG2E; att4.y *= LOG2E; att4.z *= LOG2E; att4.w *= LOG2E;
    float4 xr4 = *(const float4*)(xr + (size_t)n * 256 + lane * 4);

    int beg  = csr_off[n];       // uniform -> s_load
    int end  = csr_off[n + 1];
    int m    = end - beg;        // includes self loop, >= 1
    int last = end - 1;

    const float* __restrict__ xlp = xl + lane * 4;

    auto logit = [&](const float4& v) -> float {
        float s0 = v.x + xr4.x, s1 = v.y + xr4.y, s2 = v.z + xr4.z, s3 = v.w + xr4.w;
        float t0 = fmaxf(s0, NEG_SLOPE * s0);
        float t1 = fmaxf(s1, NEG_SLOPE * s1);
        float t2 = fmaxf(s2, NEG_SLOPE * s2);
        float t3 = fmaxf(s3, NEG_SLOPE * s3);
        return t0 * att4.x + t1 * att4.y + t2 * att4.z + t3 * att4.w;
    };

    // group 0 rows + group 1 indices (clamped -> always valid)
    int i0 = csr_src[beg];
    int i1 = csr_src[min(beg + 1, last)];
    int i2 = csr_src[min(beg + 2, last)];
    int i3 = csr_src[min(beg + 3, last)];
    float4 a0 = *(const float4*)(xlp + (size_t)i0 * 256);
    float4 a1 = *(const float4*)(xlp + (size_t)i1 * 256);
    float4 a2 = *(const float4*)(xlp + (size_t)i2 * 256);
    float4 a3 = *(const float4*)(xlp + (size_t)i3 * 256);
    int j0 = csr_src[min(beg + 4, last)];
    int j1 = csr_src[min(beg + 5, last)];
    int j2 = csr_src[min(beg + 6, last)];
    int j3 = csr_src[min(beg + 7, last)];

    float ax = 0.f, ay = 0.f, az = 0.f, aw = 0.f, denom = 0.f;

    for (int base = 0; base < m; base += 4) {
        int rem = m - base;   // wave-uniform (SGPR)
        // prefetch next group's rows + next-next indices
        float4 b0 = *(const float4*)(xlp + (size_t)j0 * 256);
        float4 b1 = *(const float4*)(xlp + (size_t)j1 * 256);
        float4 b2 = *(const float4*)(xlp + (size_t)j2 * 256);
        float4 b3 = *(const float4*)(xlp + (size_t)j3 * 256);
        int q = beg + base + 8;
        j0 = csr_src[min(q,     last)];
        j1 = csr_src[min(q + 1, last)];
        j2 = csr_src[min(q + 2, last)];
        j3 = csr_src[min(q + 3, last)];

        float p0 = logit(a0), p1 = logit(a1), p2 = logit(a2), p3 = logit(a3);
        DPP_ADD(p0, 0xB1);  DPP_ADD(p1, 0xB1);  DPP_ADD(p2, 0xB1);  DPP_ADD(p3, 0xB1);
        DPP_ADD(p0, 0x4E);  DPP_ADD(p1, 0x4E);  DPP_ADD(p2, 0x4E);  DPP_ADD(p3, 0x4E);
        DPP_ADD(p0, 0x141); DPP_ADD(p1, 0x141); DPP_ADD(p2, 0x141); DPP_ADD(p3, 0x141);
        DPP_ADD(p0, 0x140); DPP_ADD(p1, 0x140); DPP_ADD(p2, 0x140); DPP_ADD(p3, 0x140);
        float w0 = EXP2(p0);
        float w1 = (rem > 1) ? EXP2(p1) : 0.f;   // branchless tail (cndmask)
        float w2 = (rem > 2) ? EXP2(p2) : 0.f;
        float w3 = (rem > 3) ? EXP2(p3) : 0.f;

        denom += (w0 + w1) + (w2 + w3);
        ax += w0 * a0.x + w1 * a1.x + w2 * a2.x + w3 * a3.x;
        ay += w0 * a0.y + w1 * a1.y + w2 * a2.y + w3 * a3.y;
        az += w0 * a0.z + w1 * a1.z + w2 * a2.z + w3 * a3.z;
        aw += w0 * a0.w + w1 * a1.w + w2 * a2.w + w3 * a3.w;

        a0 = b0; a1 = b1; a2 = b2; a3 = b3;
    }

    float inv = 1.f / denom;
    float rx = ax * inv, ry = ay * inv, rz = az * inv, rw = aw * inv;
    // head mean: lanes j, j^16, j^32, j^48 share feature d
    rx += __shfl_xor(rx, 16); rx += __shfl_xor(rx, 32);
    ry += __shfl_xor(ry, 16); ry += __shfl_xor(ry, 32);
    rz += __shfl_xor(rz, 16); rz += __shfl_xor(rz, 32);
    rw += __shfl_xor(rw, 16); rw += __shfl_xor(rw, 32);

    if (lane < 16) {
        int d0 = lane * 4;
        float4 bv = *(const float4*)(gbias + d0);
        float ox = 0.25f * rx + bv.x;
        float oy = 0.25f * ry + bv.y;
        float oz = 0.25f * rz + bv.z;
        float ow = 0.25f * rw + bv.w;
        if (apply_gelu) {
            const float kk = 0.70710678118654752440f;
            ox = 0.5f * ox * (1.f + erff(ox * kk));
            oy = 0.5f * oy * (1.f + erff(oy * kk));
            oz = 0.5f * oz * (1.f + erff(oz * kk));
            ow = 0.5f * ow * (1.f + erff(ow * kk));
        }
        *(float4*)(xout + (size_t)n * 64 + d0) = make_float4(ox, oy, oz, ow);
    }
}

// ---------------------------------------------------------------------------
// Global mean pool (batch sorted) + classifier. Block per graph, 256 threads.
// Deterministic: fixed row->sub assignment, ordered partial combine.
// ---------------------------------------------------------------------------
__global__ __launch_bounds__(256) void pool_kernel(
        const float* __restrict__ x, const int* __restrict__ batch,
        const float* __restrict__ Wc, const float* __restrict__ bc,
        float* __restrict__ out, int N, int G) {
    __shared__ float part[4][64];
    __shared__ float pooled[64];
    int g = blockIdx.x, t = threadIdx.x;
    int sub = t >> 6, lane = t & 63;
    int lo = 0, hi = N;
    while (lo < hi) { int mid = (lo + hi) >> 1; if (batch[mid] < g) lo = mid + 1; else hi = mid; }
    int beg = lo;
    hi = N;
    while (lo < hi) { int mid = (lo + hi) >> 1; if (batch[mid] < g + 1) lo = mid + 1; else hi = mid; }
    int end = lo;

    float acc = 0.f;
    for (int n = beg + sub; n < end; n += 4) acc += x[(size_t)n * 64 + lane];
    part[sub][lane] = acc;
    __syncthreads();
    if (t < 64) {
        float s = (part[0][t] + part[1][t]) + (part[2][t] + part[3][t]);
        int cnt = end - beg;
        pooled[t] = (cnt > 0) ? s / (float)cnt : 0.f;
    }
    __syncthreads();
    if (t < 10) {
        float o = bc[t];
        for (int d = 0; d < 64; ++d) o += pooled[d] * Wc[d * 10 + t];
        out[(size_t)g * 10 + t] = o;
    }
}

// ---------------------------------------------------------------------------
extern "C" void kernel_launch(void* const* d_in, const int* in_sizes, int n_in,
                              void* d_out, int out_size, void* d_ws, size_t ws_size,
                              hipStream_t stream) {
    const int*   feat  = (const int*)d_in[0];
    const int*   edges = (const int*)d_in[1];
    const int*   batch = (const int*)d_in[2];
    const float* emb   = (const float*)d_in[3];
    const float* Wl    = (const float*)d_in[4];
    const float* bl    = (const float*)d_in[5];
    const float* Wr    = (const float*)d_in[6];
    const float* br    = (const float*)d_in[7];
    const float* att   = (const float*)d_in[8];
    const float* gb    = (const float*)d_in[9];
    const float* Wc    = (const float*)d_in[10];
    const float* bc    = (const float*)d_in[11];
    float* out = (float*)d_out;

    const int N = in_sizes[2];
    const int E = in_sizes[1] / 2;
    const int G = out_size / 10;

    char* ws = (char*)d_ws;
    size_t off = 0;
    auto alloc = [&](size_t bytes) -> char* {
        char* p = ws + off;
        off = (off + bytes + 255) & ~(size_t)255;
        return p;
    };
    float* x         = (float*)alloc((size_t)N * 64 * 4);
    float* xl        = (float*)alloc((size_t)N * 256 * 4);
    float* xr        = (float*)alloc((size_t)N * 256 * 4);
    int*   counts    = (int*)alloc((size_t)N * 4);
    int*   csr_off   = (int*)alloc((size_t)(N + 8) * 4);
    int*   cursor    = (int*)alloc((size_t)N * 4);
    int*   csr_src   = (int*)alloc((size_t)(E + N + 64) * 4);
    int*   blockSums = (int*)alloc(256 * 4);

    const int* srcv = edges;
    const int* dstv = edges + E;

    // 1) zero counts, fused embed + histogram
    hipMemsetAsync(counts, 0, (size_t)N * 4, stream);
    hipLaunchKernelGGL(embed_kernel, dim3((N + 3) / 4), dim3(256), 0, stream,
                       feat, emb, dstv, counts, x, N, E);

    // 2) CSR by destination, self-loop at each segment head (+1 in scan)
    int nb = (N + 1023) / 1024;
    hipLaunchKernelGGL(scan_block_kernel, dim3(nb), dim3(256), 0, stream, counts, csr_off, blockSums, N);
    hipLaunchKernelGGL(scan_sums_kernel, dim3(1), dim3(64), 0, stream, blockSums, nb);
    hipLaunchKernelGGL(finalize_kernel, dim3((N + 255) / 256), dim3(256), 0, stream,
                       csr_off, blockSums, cursor, csr_src, N, E + N);
    hipLaunchKernelGGL(scatter_kernel, dim3((E + 255) / 256), dim3(256), 0, stream, srcv, dstv, cursor, csr_src, E);

    // 3) GATv2 layers
    for (int l = 0; l < 3; ++l) {
        hipLaunchKernelGGL(gemm_kernel, dim3((N + 63) / 64, 4), dim3(256), 0, stream,
                           x, Wl + (size_t)l * 64 * 256, Wr + (size_t)l * 64 * 256,
                           bl + l * 256, br + l * 256, xl, xr, N);
        hipLaunchKernelGGL(agg_kernel, dim3((N + 3) / 4), dim3(256), 0, stream,
                           xl, xr, csr_off, csr_src, att + l * 256, gb + l * 64,
                           x, N, (l < 2) ? 1 : 0);
    }

    // 4) pool + classify
    hipLaunchKernelGGL(pool_kernel, dim3(G), dim3(256), 0, stream, x, batch, Wc, bc, out, N, G);
}

// Round 7
// 514.210 us; speedup vs baseline: 1.0692x; 1.0223x over previous
//
#include <hip/hip_runtime.h>
#include <math.h>

#define NEG_SLOPE 0.2f
#define LOG2E 1.44269504088896340736f

#if __has_builtin(__builtin_amdgcn_exp2f)
#define EXP2(x) __builtin_amdgcn_exp2f(x)
#else
#define EXP2(x) exp2f(x)
#endif

// in-wave butterfly add via DPP (plain VALU, no DS pipe): validated R5/R6.
#define DPP_ADD(p, ctrl) \
    p += __int_as_float(__builtin_amdgcn_update_dpp(0, __float_as_int(p), ctrl, 0xf, 0xf, true))

// ---------------------------------------------------------------------------
// AtomEncoder + edge histogram (fused).
// ---------------------------------------------------------------------------
__global__ __launch_bounds__(256) void embed_kernel(
        const int* __restrict__ feat, const float* __restrict__ emb,
        const int* __restrict__ dstE, int* __restrict__ counts,
        float* __restrict__ x, int N, int E) {
    int gid = blockIdx.x * 256 + threadIdx.x;
    if (gid < E) atomicAdd(&counts[dstE[gid]], 1);

    const int offs[9] = {0, 119, 124, 136, 148, 158, 164, 170, 172};
    int sub  = threadIdx.x >> 6;
    int lane = threadIdx.x & 63;
    int n = __builtin_amdgcn_readfirstlane(blockIdx.x * 4 + sub);
    if (n >= N) return;
    float s = 0.f;
#pragma unroll
    for (int j = 0; j < 9; ++j) {
        int idx = feat[n * 9 + j] + offs[j];
        s += emb[idx * 64 + lane];
    }
    x[(size_t)n * 64 + lane] = s;
}

// ---------------------------------------------------------------------------
// Dual GEMM v2: tile 128x128, 256 threads, 8x8 register block per thread
// (64 FMA per 4 ds_read_b128 -- 2x the FMA:DS ratio of the old 8x4).
// BK=32, two K-phases. LDS 32 KB/block.
// ---------------------------------------------------------------------------
__global__ __launch_bounds__(256) void gemm_kernel(
        const float* __restrict__ x,
        const float* __restrict__ Wl, const float* __restrict__ Wr,
        const float* __restrict__ bl, const float* __restrict__ br,
        float* __restrict__ xl, float* __restrict__ xr, int N) {
    __shared__ __align__(16) float As[32][128];   // [k][m] 16 KB
    __shared__ __align__(16) float Bs[32][128];   // [k][c] 16 KB
    int t  = threadIdx.x;
    int m0 = blockIdx.x * 128;
    int ct = blockIdx.y;  // 0,1 -> Wl ; 2,3 -> Wr
    const float* B    = (ct < 2) ? Wl : Wr;
    const float* bias = (ct < 2) ? bl : br;
    float*       out  = (ct < 2) ? xl : xr;
    int cb = (ct & 1) * 128;

    int lrow = t >> 1;        // A-load: row within tile (0..127)
    int lq0  = (t & 1) * 4;   // A-load: first k-quad of this phase (0 or 4)
    int c4   = t & 31;        // B-load: col quad
    int k0   = t >> 5;        // B-load: k row 0..7
    int rg   = t >> 4;        // compute: row group (8 rows)  0..15
    int cg   = t & 15;        // compute: col group (8 cols)  0..15

    float4 acc[16];           // [r][half]: acc[r*2+h]
#pragma unroll
    for (int i = 0; i < 16; ++i) acc[i] = make_float4(0.f, 0.f, 0.f, 0.f);

    int arow = m0 + lrow;
#pragma unroll
    for (int kb = 0; kb < 2; ++kb) {
        float4 av[4];
#pragma unroll
        for (int j = 0; j < 4; ++j) {
            av[j] = make_float4(0.f, 0.f, 0.f, 0.f);
            if (arow < N)
                av[j] = *(const float4*)(x + (size_t)arow * 64 + kb * 32 + (lq0 + j) * 4);
        }
        float4 bv[4];
#pragma unroll
        for (int j = 0; j < 4; ++j)
            bv[j] = *(const float4*)(B + (size_t)(kb * 32 + k0 + j * 8) * 256 + cb + c4 * 4);

        if (kb) __syncthreads();   // previous phase fully consumed
#pragma unroll
        for (int j = 0; j < 4; ++j) {
            int kq = lq0 + j;
            As[kq * 4 + 0][lrow] = av[j].x;
            As[kq * 4 + 1][lrow] = av[j].y;
            As[kq * 4 + 2][lrow] = av[j].z;
            As[kq * 4 + 3][lrow] = av[j].w;
        }
#pragma unroll
        for (int j = 0; j < 4; ++j)
            *(float4*)(&Bs[k0 + j * 8][c4 * 4]) = bv[j];
        __syncthreads();

#pragma unroll 2
        for (int k = 0; k < 32; ++k) {
            float4 b0 = *(const float4*)(&Bs[k][cg * 8]);
            float4 b1 = *(const float4*)(&Bs[k][cg * 8 + 4]);
            float4 a0 = *(const float4*)(&As[k][rg * 8]);
            float4 a1 = *(const float4*)(&As[k][rg * 8 + 4]);
            float ar[8] = {a0.x, a0.y, a0.z, a0.w, a1.x, a1.y, a1.z, a1.w};
#pragma unroll
            for (int r = 0; r < 8; ++r) {
                acc[r * 2].x     += ar[r] * b0.x; acc[r * 2].y     += ar[r] * b0.y;
                acc[r * 2].z     += ar[r] * b0.z; acc[r * 2].w     += ar[r] * b0.w;
                acc[r * 2 + 1].x += ar[r] * b1.x; acc[r * 2 + 1].y += ar[r] * b1.y;
                acc[r * 2 + 1].z += ar[r] * b1.z; acc[r * 2 + 1].w += ar[r] * b1.w;
            }
        }
    }

    float4 bb0 = *(const float4*)(bias + cb + cg * 8);
    float4 bb1 = *(const float4*)(bias + cb + cg * 8 + 4);
#pragma unroll
    for (int r = 0; r < 8; ++r) {
        int row = m0 + rg * 8 + r;
        if (row < N) {
            float4 o0 = acc[r * 2], o1 = acc[r * 2 + 1];
            o0.x += bb0.x; o0.y += bb0.y; o0.z += bb0.z; o0.w += bb0.w;
            o1.x += bb1.x; o1.y += bb1.y; o1.z += bb1.z; o1.w += bb1.w;
            *(float4*)(out + (size_t)row * 256 + cb + cg * 8)     = o0;
            *(float4*)(out + (size_t)row * 256 + cb + cg * 8 + 4) = o1;
        }
    }
}

// ---------------------------------------------------------------------------
// CSR build (self loop at each segment head, +1 folded into scan)
// ---------------------------------------------------------------------------
__global__ void scan_block_kernel(const int* __restrict__ counts, int* __restrict__ excl,
                                  int* __restrict__ blockSums, int N) {
    __shared__ int lds[256];
    int b = blockIdx.x, t = threadIdx.x;
    int base = b * 1024 + t * 4;
    int v0 = (base + 0 < N) ? counts[base + 0] + 1 : 0;
    int v1 = (base + 1 < N) ? counts[base + 1] + 1 : 0;
    int v2 = (base + 2 < N) ? counts[base + 2] + 1 : 0;
    int v3 = (base + 3 < N) ? counts[base + 3] + 1 : 0;
    int s = v0 + v1 + v2 + v3;
    lds[t] = s;
    __syncthreads();
    for (int off = 1; off < 256; off <<= 1) {
        int add = (t >= off) ? lds[t - off] : 0;
        __syncthreads();
        lds[t] += add;
        __syncthreads();
    }
    int run = lds[t] - s;
    if (base + 0 < N) excl[base + 0] = run; run += v0;
    if (base + 1 < N) excl[base + 1] = run; run += v1;
    if (base + 2 < N) excl[base + 2] = run; run += v2;
    if (base + 3 < N) excl[base + 3] = run;
    if (t == 255) blockSums[b] = lds[255];
}

__global__ void scan_sums_kernel(int* __restrict__ blockSums, int nb) {
    __shared__ int lds[64];
    int t = threadIdx.x;  // nb <= 64 (N <= 65536)
    int v = (t < nb) ? blockSums[t] : 0;
    lds[t] = v;
    __syncthreads();
    for (int off = 1; off < 64; off <<= 1) {
        int add = (t >= off) ? lds[t - off] : 0;
        __syncthreads();
        lds[t] += add;
        __syncthreads();
    }
    if (t < nb) blockSums[t] = lds[t] - v;
}

__global__ void finalize_kernel(int* __restrict__ csr_off, const int* __restrict__ blockSums,
                                int* __restrict__ cursor, int* __restrict__ csr_src,
                                int N, int total) {
    int i = blockIdx.x * 256 + threadIdx.x;
    if (i < N) {
        int v = csr_off[i] + blockSums[i >> 10];
        csr_off[i] = v;
        csr_src[v] = i;    // self loop at segment head
        cursor[i]  = v + 1;
    }
    if (i == 0) csr_off[N] = total;
}

__global__ void scatter_kernel(const int* __restrict__ src, const int* __restrict__ dst,
                               int* __restrict__ cursor, int* __restrict__ csr_src, int E) {
    int e = blockIdx.x * 256 + threadIdx.x;
    if (e < E) {
        int pos = atomicAdd(&cursor[dst[e]], 1);
        csr_src[pos] = src[e];
    }
}

// ---------------------------------------------------------------------------
// GATv2 aggregation v4: one wave per dst node; 3-buffer rotating software
// pipeline (unroll-by-3 ping-pong, no register moves): each 4-edge block's
// row gathers are issued ~2 compute-blocks before use, with 8 row loads
// outstanding at every wait point. Indices prefetched one block further.
// Wave-uniform early-exits keep slot count 4-granular. DPP head reduction.
// ---------------------------------------------------------------------------
__global__ __launch_bounds__(256) void agg_kernel(
        const float* __restrict__ xl, const float* __restrict__ xr,
        const int* __restrict__ csr_off, const int* __restrict__ csr_src,
        const float* __restrict__ att,   // [4*64] this layer
        const float* __restrict__ gbias, // [64] this layer
        float* __restrict__ xout, int N, int apply_gelu) {
    int wave = threadIdx.x >> 6;
    int lane = threadIdx.x & 63;
    int n = __builtin_amdgcn_readfirstlane(blockIdx.x * 4 + wave);
    if (n >= N) return;

    float4 att4 = ((const float4*)att)[lane];
    att4.x *= LOG2E; att4.y *= LOG2E; att4.z *= LOG2E; att4.w *= LOG2E;
    float4 xr4 = *(const float4*)(xr + (size_t)n * 256 + lane * 4);

    int beg  = csr_off[n];       // uniform -> s_load
    int end  = csr_off[n + 1];
    int m    = end - beg;        // includes self loop, >= 1
    int last = end - 1;

    const float* __restrict__ xlp = xl + lane * 4;

    auto idx4 = [&](int pos) -> int4 {
        int4 v;
        v.x = csr_src[min(pos,     last)];
        v.y = csr_src[min(pos + 1, last)];
        v.z = csr_src[min(pos + 2, last)];
        v.w = csr_src[min(pos + 3, last)];
        return v;
    };
    auto rows4 = [&](const int4& iv, float4& r0, float4& r1, float4& r2, float4& r3) {
        r0 = *(const float4*)(xlp + (size_t)iv.x * 256);
        r1 = *(const float4*)(xlp + (size_t)iv.y * 256);
        r2 = *(const float4*)(xlp + (size_t)iv.z * 256);
        r3 = *(const float4*)(xlp + (size_t)iv.w * 256);
    };
    auto logit = [&](const float4& v) -> float {
        float s0 = v.x + xr4.x, s1 = v.y + xr4.y, s2 = v.z + xr4.z, s3 = v.w + xr4.w;
        float t0 = fmaxf(s0, NEG_SLOPE * s0);
        float t1 = fmaxf(s1, NEG_SLOPE * s1);
        float t2 = fmaxf(s2, NEG_SLOPE * s2);
        float t3 = fmaxf(s3, NEG_SLOPE * s3);
        return t0 * att4.x + t1 * att4.y + t2 * att4.z + t3 * att4.w;
    };

    float ax = 0.f, ay = 0.f, az = 0.f, aw = 0.f, denom = 0.f;

    auto compute4 = [&](const float4& e0, const float4& e1, const float4& e2,
                        const float4& e3, int kbase) {
        float p0 = logit(e0), p1 = logit(e1), p2 = logit(e2), p3 = logit(e3);
        DPP_ADD(p0, 0xB1);  DPP_ADD(p1, 0xB1);  DPP_ADD(p2, 0xB1);  DPP_ADD(p3, 0xB1);
        DPP_ADD(p0, 0x4E);  DPP_ADD(p1, 0x4E);  DPP_ADD(p2, 0x4E);  DPP_ADD(p3, 0x4E);
        DPP_ADD(p0, 0x141); DPP_ADD(p1, 0x141); DPP_ADD(p2, 0x141); DPP_ADD(p3, 0x141);
        DPP_ADD(p0, 0x140); DPP_ADD(p1, 0x140); DPP_ADD(p2, 0x140); DPP_ADD(p3, 0x140);
        float w0 = EXP2(p0);                            // slot 0 always valid
        float w1 = (kbase + 1 < m) ? EXP2(p1) : 0.f;    // branchless tail
        float w2 = (kbase + 2 < m) ? EXP2(p2) : 0.f;
        float w3 = (kbase + 3 < m) ? EXP2(p3) : 0.f;
        denom += (w0 + w1) + (w2 + w3);
        ax += w0 * e0.x + w1 * e1.x + w2 * e2.x + w3 * e3.x;
        ay += w0 * e0.y + w1 * e1.y + w2 * e2.y + w3 * e3.y;
        az += w0 * e0.z + w1 * e1.z + w2 * e2.z + w3 * e3.z;
        aw += w0 * e0.w + w1 * e1.w + w2 * e2.w + w3 * e3.w;
    };

    // pipeline prologue: 3 row-buffers + 3 index-prefetch regs
    float4 a0, a1, a2, a3, b0, b1, b2, b3, c0, c1, c2, c3;
    rows4(idx4(beg),     a0, a1, a2, a3);
    rows4(idx4(beg + 4), b0, b1, b2, b3);
    rows4(idx4(beg + 8), c0, c1, c2, c3);
    int4 ja = idx4(beg + 12);
    int4 jb = idx4(beg + 16);
    int4 jc = idx4(beg + 20);

    int g = 0;
    while (true) {
        compute4(a0, a1, a2, a3, g);
        if (g + 4 >= m) break;
        rows4(ja, a0, a1, a2, a3);  ja = idx4(beg + g + 24);

        compute4(b0, b1, b2, b3, g + 4);
        if (g + 8 >= m) break;
        rows4(jb, b0, b1, b2, b3);  jb = idx4(beg + g + 28);

        compute4(c0, c1, c2, c3, g + 8);
        if (g + 12 >= m) break;
        rows4(jc, c0, c1, c2, c3);  jc = idx4(beg + g + 32);

        g += 12;
    }

    float inv = 1.f / denom;
    float rx = ax * inv, ry = ay * inv, rz = az * inv, rw = aw * inv;
    // head mean: lanes j, j^16, j^32, j^48 share feature d
    rx += __shfl_xor(rx, 16); rx += __shfl_xor(rx, 32);
    ry += __shfl_xor(ry, 16); ry += __shfl_xor(ry, 32);
    rz += __shfl_xor(rz, 16); rz += __shfl_xor(rz, 32);
    rw += __shfl_xor(rw, 16); rw += __shfl_xor(rw, 32);

    if (lane < 16) {
        int d0 = lane * 4;
        float4 bv = *(const float4*)(gbias + d0);
        float ox = 0.25f * rx + bv.x;
        float oy = 0.25f * ry + bv.y;
        float oz = 0.25f * rz + bv.z;
        float ow = 0.25f * rw + bv.w;
        if (apply_gelu) {
            const float kk = 0.70710678118654752440f;
            ox = 0.5f * ox * (1.f + erff(ox * kk));
            oy = 0.5f * oy * (1.f + erff(oy * kk));
            oz = 0.5f * oz * (1.f + erff(oz * kk));
            ow = 0.5f * ow * (1.f + erff(ow * kk));
        }
        *(float4*)(xout + (size_t)n * 64 + d0) = make_float4(ox, oy, oz, ow);
    }
}

// ---------------------------------------------------------------------------
// Global mean pool (batch sorted) + classifier. Block per graph, 256 threads.
// ---------------------------------------------------------------------------
__global__ __launch_bounds__(256) void pool_kernel(
        const float* __restrict__ x, const int* __restrict__ batch,
        const float* __restrict__ Wc, const float* __restrict__ bc,
        float* __restrict__ out, int N, int G) {
    __shared__ float part[4][64];
    __shared__ float pooled[64];
    int g = blockIdx.x, t = threadIdx.x;
    int sub = t >> 6, lane = t & 63;
    int lo = 0, hi = N;
    while (lo < hi) { int mid = (lo + hi) >> 1; if (batch[mid] < g) lo = mid + 1; else hi = mid; }
    int beg = lo;
    hi = N;
    while (lo < hi) { int mid = (lo + hi) >> 1; if (batch[mid] < g + 1) lo = mid + 1; else hi = mid; }
    int end = lo;

    float acc = 0.f;
    for (int n = beg + sub; n < end; n += 4) acc += x[(size_t)n * 64 + lane];
    part[sub][lane] = acc;
    __syncthreads();
    if (t < 64) {
        float s = (part[0][t] + part[1][t]) + (part[2][t] + part[3][t]);
        int cnt = end - beg;
        pooled[t] = (cnt > 0) ? s / (float)cnt : 0.f;
    }
    __syncthreads();
    if (t < 10) {
        float o = bc[t];
        for (int d = 0; d < 64; ++d) o += pooled[d] * Wc[d * 10 + t];
        out[(size_t)g * 10 + t] = o;
    }
}

// ---------------------------------------------------------------------------
extern "C" void kernel_launch(void* const* d_in, const int* in_sizes, int n_in,
                              void* d_out, int out_size, void* d_ws, size_t ws_size,
                              hipStream_t stream) {
    const int*   feat  = (const int*)d_in[0];
    const int*   edges = (const int*)d_in[1];
    const int*   batch = (const int*)d_in[2];
    const float* emb   = (const float*)d_in[3];
    const float* Wl    = (const float*)d_in[4];
    const float* bl    = (const float*)d_in[5];
    const float* Wr    = (const float*)d_in[6];
    const float* br    = (const float*)d_in[7];
    const float* att   = (const float*)d_in[8];
    const float* gb    = (const float*)d_in[9];
    const float* Wc    = (const float*)d_in[10];
    const float* bc    = (const float*)d_in[11];
    float* out = (float*)d_out;

    const int N = in_sizes[2];
    const int E = in_sizes[1] / 2;
    const int G = out_size / 10;

    char* ws = (char*)d_ws;
    size_t off = 0;
    auto alloc = [&](size_t bytes) -> char* {
        char* p = ws + off;
        off = (off + bytes + 255) & ~(size_t)255;
        return p;
    };
    float* x         = (float*)alloc((size_t)N * 64 * 4);
    float* xl        = (float*)alloc((size_t)N * 256 * 4);
    float* xr        = (float*)alloc((size_t)N * 256 * 4);
    int*   counts    = (int*)alloc((size_t)N * 4);
    int*   csr_off   = (int*)alloc((size_t)(N + 8) * 4);
    int*   cursor    = (int*)alloc((size_t)N * 4);
    int*   csr_src   = (int*)alloc((size_t)(E + N + 64) * 4);
    int*   blockSums = (int*)alloc(256 * 4);

    const int* srcv = edges;
    const int* dstv = edges + E;

    // 1) zero counts, fused embed + histogram
    hipMemsetAsync(counts, 0, (size_t)N * 4, stream);
    hipLaunchKernelGGL(embed_kernel, dim3((N + 3) / 4), dim3(256), 0, stream,
                       feat, emb, dstv, counts, x, N, E);

    // 2) CSR by destination, self-loop at each segment head (+1 in scan)
    int nb = (N + 1023) / 1024;
    hipLaunchKernelGGL(scan_block_kernel, dim3(nb), dim3(256), 0, stream, counts, csr_off, blockSums, N);
    hipLaunchKernelGGL(scan_sums_kernel, dim3(1), dim3(64), 0, stream, blockSums, nb);
    hipLaunchKernelGGL(finalize_kernel, dim3((N + 255) / 256), dim3(256), 0, stream,
                       csr_off, blockSums, cursor, csr_src, N, E + N);
    hipLaunchKernelGGL(scatter_kernel, dim3((E + 255) / 256), dim3(256), 0, stream, srcv, dstv, cursor, csr_src, E);

    // 3) GATv2 layers
    for (int l = 0; l < 3; ++l) {
        hipLaunchKernelGGL(gemm_kernel, dim3((N + 127) / 128, 4), dim3(256), 0, stream,
                           x, Wl + (size_t)l * 64 * 256, Wr + (size_t)l * 64 * 256,
                           bl + l * 256, br + l * 256, xl, xr, N);
        hipLaunchKernelGGL(agg_kernel, dim3((N + 3) / 4), dim3(256), 0, stream,
                           xl, xr, csr_off, csr_src, att + l * 256, gb + l * 64,
                           x, N, (l < 2) ? 1 : 0);
    }

    // 4) pool + classify
    hipLaunchKernelGGL(pool_kernel, dim3(G), dim3(256), 0, stream, x, batch, Wc, bc, out, N, G);
}